// Round 2
// baseline (605.605 us; speedup 1.0000x reference)
//
#include <hip/hip_runtime.h>

// AttentionBasedNN: 4-layer additive (Bahdanau) attention + residual FCs + head.
// VEC=1280, HID=128, B=4, S=256. fp32 (no fp32 MFMA on CDNA4 -> vector ALU).
//
// Round-2 structure: no memsets, no atomics. Split-K GEMMs write disjoint
// partial buffers; the partial sum is folded into the consumer kernel
// (scores8_k for QK, FC2's A-load for FC1, tail4_k for layer-4 K-proj).
// 20 dispatches total.

#define DEV __device__ __forceinline__

static constexpr int VEC = 1280;
static constexpr int HID = 128;
static constexpr int BB  = 4;
static constexpr int SS  = 256;
static constexpr int MROWS = BB * SS;   // 1024

DEV float ftanh(float x) {
  // tanh(x) = 1 - 2/(exp(2x)+1); exp->inf gives +1, exp->0 gives -1.
  float e = __expf(2.0f * x);
  return 1.0f - __fdividef(2.0f, e + 1.0f);
}

DEV float waveSum(float v) {
#pragma unroll
  for (int off = 32; off > 0; off >>= 1) v += __shfl_xor(v, off, 64);
  return v;
}
DEV float waveMax(float v) {
#pragma unroll
  for (int off = 32; off > 0; off >>= 1) v = fmaxf(v, __shfl_xor(v, off, 64));
  return v;
}
// blockDim.x == 256 (4 waves) everywhere these are used.
DEV float blockSum(float v, float* red) {
  v = waveSum(v);
  int tid = threadIdx.x;
  if ((tid & 63) == 0) red[tid >> 6] = v;
  __syncthreads();
  float r = (red[0] + red[1]) + (red[2] + red[3]);
  __syncthreads();
  return r;
}
DEV float blockMax(float v, float* red) {
  v = waveMax(v);
  int tid = threadIdx.x;
  if ((tid & 63) == 0) red[tid >> 6] = v;
  __syncthreads();
  float r = fmaxf(fmaxf(red[0], red[1]), fmaxf(red[2], red[3]));
  __syncthreads();
  return r;
}

// ---------------------------------------------------------------------------
// fp32 GEMM, 64x64 tile, BK=16, 256 threads, 4x4 microtile.
// MODE==0: blockIdx.z = batch (A,B offset by z*sAb/z*sBb; C and res by z*sCb).
// MODE==1: blockIdx.z = K-split slice (kChunk each); C offset by z*sCb into a
//          DISJOINT partial buffer (plain store — consumer sums partials).
// AFUSE: A is the sum of 4 partial buffers (stride aPart) + aBias, ReLU'd.
// Dual-B: output col n < nSplitB reads B0, else B1 at col n-nSplitB (same ldB).
// ---------------------------------------------------------------------------
template <int MODE, bool AFUSE, bool OBIAS, bool ORES>
__global__ __launch_bounds__(256) void gemm_k(
    const float* __restrict__ A, long sAb, long aPart,
    const float* __restrict__ B0, const float* __restrict__ B1, int nSplitB,
    long sBb, int ldB,
    float* __restrict__ C, long sCb,
    const float* __restrict__ aBias, const float* __restrict__ oBias,
    const float* __restrict__ res,
    int N, int K, int kChunk) {
  const int n0 = blockIdx.x * 64;
  const int m0 = blockIdx.y * 64;
  const int z  = blockIdx.z;

  const float* Ab = A + (MODE == 0 ? (long)z * sAb : 0L);
  float*       Cb = C + (long)z * sCb;
  const float* resz = ORES ? (res + (MODE == 0 ? (long)z * sCb : 0L)) : nullptr;
  const float* Bsel;
  int nb;
  if (n0 < nSplitB) { Bsel = B0; nb = n0; } else { Bsel = B1; nb = n0 - nSplitB; }
  Bsel += (MODE == 0 ? (long)z * sBb : 0L);

  const int kBeg = (MODE == 1) ? z * kChunk : 0;
  const int kEnd = (MODE == 1) ? kBeg + kChunk : K;

  __shared__ float As[16][68];  // [k][m]
  __shared__ float Bs[16][68];  // [k][n]

  const int tid = threadIdx.x;
  const int tx = tid & 15, ty = tid >> 4;
  const int ar = tid >> 2, ac = (tid & 3) << 2;   // A: row 0..63, k-col {0,4,8,12}
  const int br = tid >> 4, bc = (tid & 15) << 2;  // B: k-row 0..15, col 0..60

  float acc[4][4] = {};

  for (int kt = kBeg; kt < kEnd; kt += 16) {
    const size_t aoff = (size_t)(m0 + ar) * K + kt + ac;
    float4 a4;
    if (AFUSE) {
      float4 p0 = *(const float4*)(Ab + aoff);
      float4 p1 = *(const float4*)(Ab + aPart + aoff);
      float4 p2 = *(const float4*)(Ab + 2 * aPart + aoff);
      float4 p3 = *(const float4*)(Ab + 3 * aPart + aoff);
      float4 bz = *(const float4*)(aBias + kt + ac);
      a4.x = fmaxf(p0.x + p1.x + p2.x + p3.x + bz.x, 0.0f);
      a4.y = fmaxf(p0.y + p1.y + p2.y + p3.y + bz.y, 0.0f);
      a4.z = fmaxf(p0.z + p1.z + p2.z + p3.z + bz.z, 0.0f);
      a4.w = fmaxf(p0.w + p1.w + p2.w + p3.w + bz.w, 0.0f);
    } else {
      a4 = *(const float4*)(Ab + aoff);
    }
    float4 b4 = *(const float4*)(Bsel + (size_t)(kt + br) * ldB + nb + bc);
    __syncthreads();
    As[ac + 0][ar] = a4.x;
    As[ac + 1][ar] = a4.y;
    As[ac + 2][ar] = a4.z;
    As[ac + 3][ar] = a4.w;
    *(float4*)&Bs[br][bc] = b4;
    __syncthreads();
#pragma unroll
    for (int kk = 0; kk < 16; ++kk) {
      const float4 av = *(const float4*)&As[kk][ty << 2];
      const float4 bv = *(const float4*)&Bs[kk][tx << 2];
      const float a[4] = {av.x, av.y, av.z, av.w};
      const float b[4] = {bv.x, bv.y, bv.z, bv.w};
#pragma unroll
      for (int i = 0; i < 4; ++i)
#pragma unroll
        for (int j = 0; j < 4; ++j) acc[i][j] = fmaf(a[i], b[j], acc[i][j]);
    }
  }

#pragma unroll
  for (int i = 0; i < 4; ++i) {
    const int m = m0 + (ty << 2) + i;
#pragma unroll
    for (int j = 0; j < 4; ++j) {
      const int n = n0 + (tx << 2) + j;
      float v = acc[i][j];
      if (OBIAS) v += oBias[n];
      if (ORES) v += resz[(size_t)m * N + n];
      Cb[(size_t)m * N + n] = v;
    }
  }
}

// ---------------------------------------------------------------------------
// Scores + softmax, layers 1-3. Block = (i-tile of 8 rows, b); 256 threads.
// QKp: 4 disjoint K-split partials (stride pStride), layout [1024][256]
// with cols [0,128)=Q proj, [128,256)=K proj. Sum of partials done inline.
// Thread j handles key j for all 8 query rows (K-row read once per 8 rows).
// ---------------------------------------------------------------------------
__global__ __launch_bounds__(256) void scores8_k(const float* __restrict__ QKp,
                                                 long pStride,
                                                 const float* __restrict__ wv,
                                                 float* __restrict__ attn) {
  const int b = blockIdx.y;
  const int i0 = blockIdx.x * 8;
  const int tid = threadIdx.x;
  __shared__ float qs[8][128];
  __shared__ float wvs[128];
  __shared__ float red[4];
  for (int idx = tid; idx < 1024; idx += 256) {
    const int r = idx >> 7, h = idx & 127;
    const size_t off = ((size_t)(b * 256 + i0 + r)) * 256 + h;
    qs[r][h] = QKp[off] + QKp[pStride + off] + QKp[2 * pStride + off] +
               QKp[3 * pStride + off];
  }
  if (tid < 128) wvs[tid] = wv[tid];
  __syncthreads();

  const size_t kb = ((size_t)(b * 256 + tid)) * 256 + 128;
  float s[8] = {0, 0, 0, 0, 0, 0, 0, 0};
  for (int h = 0; h < 128; h += 4) {
    float4 k0 = *(const float4*)(QKp + kb + h);
    float4 k1 = *(const float4*)(QKp + pStride + kb + h);
    float4 k2 = *(const float4*)(QKp + 2 * pStride + kb + h);
    float4 k3 = *(const float4*)(QKp + 3 * pStride + kb + h);
    const float kx = k0.x + k1.x + k2.x + k3.x;
    const float ky = k0.y + k1.y + k2.y + k3.y;
    const float kz = k0.z + k1.z + k2.z + k3.z;
    const float kw = k0.w + k1.w + k2.w + k3.w;
    const float w0 = wvs[h], w1 = wvs[h + 1], w2 = wvs[h + 2], w3 = wvs[h + 3];
#pragma unroll
    for (int r = 0; r < 8; ++r) {
      s[r] += w0 * ftanh(qs[r][h] + kx) + w1 * ftanh(qs[r][h + 1] + ky) +
              w2 * ftanh(qs[r][h + 2] + kz) + w3 * ftanh(qs[r][h + 3] + kw);
    }
  }
#pragma unroll
  for (int r = 0; r < 8; ++r) {
    const float mx = blockMax(s[r], red);
    const float e = __expf(s[r] - mx);
    const float tot = blockSum(e, red);
    attn[((size_t)(b * 256 + i0 + r)) * 256 + tid] = e / tot;
  }
}

// LN over rows of A (residual already folded in by PV epilogue).
__global__ __launch_bounds__(256) void ln1_k(const float* __restrict__ A,
                                             float* __restrict__ Y) {
  __shared__ float red[4];
  const int r = blockIdx.x, tid = threadIdx.x;
  const float* a = A + (size_t)r * VEC;
  float v[5];
  float sum = 0.0f;
#pragma unroll
  for (int k = 0; k < 5; ++k) {
    v[k] = a[tid + k * 256];
    sum += v[k];
  }
  sum = blockSum(sum, red);
  const float m = sum * (1.0f / VEC);
  float sq = 0.0f;
#pragma unroll
  for (int k = 0; k < 5; ++k) {
    const float dl = v[k] - m;
    sq += dl * dl;
  }
  sq = blockSum(sq, red);
  const float rstd = rsqrtf(sq * (1.0f / VEC) + 1e-5f);
  float* y = Y + (size_t)r * VEC;
#pragma unroll
  for (int k = 0; k < 5; ++k) y[tid + k * 256] = (v[k] - m) * rstd;
}

// ---------------------------------------------------------------------------
// Layer-4 fused tail: q-proj (row lys only) + scores + softmax + PV +
// residual + LN + 3-layer head MLP. One block per batch b, 256 threads.
// K4p: 4 K-split partials of X3 @ Wk4, layout [1024][128], stride pStride.
// ---------------------------------------------------------------------------
__global__ __launch_bounds__(256) void tail4_k(
    const float* __restrict__ K4p, long pStride,
    const float* __restrict__ X3, const float* __restrict__ Wq4,
    const float* __restrict__ wv4, const int* __restrict__ lys,
    const float* __restrict__ hW1, const float* __restrict__ hb1,
    const float* __restrict__ hW2, const float* __restrict__ hb2,
    const float* __restrict__ hW3, const float* __restrict__ hb3,
    float* __restrict__ out) {
  const int b = blockIdx.x, tid = threadIdx.x;
  __shared__ float xrow[1280];
  __shared__ float qs[128], wvs[128];
  __shared__ float aw[256], partial[256];
  __shared__ float red[4];
  __shared__ float h1s[32], h2s[12];
  const int lp = lys[0];

  for (int k = tid; k < 1280; k += 256)
    xrow[k] = X3[((size_t)(b * 256 + lp)) * VEC + k];
  if (tid < 128) wvs[tid] = wv4[tid];
  __syncthreads();

  // q[h] = dot(xrow, Wq4[:,h]); two 640-length halves per h, then combine.
  {
    const int s = tid >> 7, h = tid & 127;
    float acc = 0.0f;
    const int k0 = s * 640;
    for (int k = k0; k < k0 + 640; ++k)
      acc = fmaf(xrow[k], Wq4[(size_t)k * HID + h], acc);
    partial[tid] = acc;
  }
  __syncthreads();
  if (tid < 128) qs[tid] = partial[tid] + partial[tid + 128];
  __syncthreads();

  // scores: thread j = tid over keys.
  const size_t kb = ((size_t)(b * 256 + tid)) * 128;
  float s = 0.0f;
  for (int h = 0; h < 128; h += 4) {
    float4 k0 = *(const float4*)(K4p + kb + h);
    float4 k1 = *(const float4*)(K4p + pStride + kb + h);
    float4 k2 = *(const float4*)(K4p + 2 * pStride + kb + h);
    float4 k3 = *(const float4*)(K4p + 3 * pStride + kb + h);
    s += wvs[h + 0] * ftanh(qs[h + 0] + k0.x + k1.x + k2.x + k3.x);
    s += wvs[h + 1] * ftanh(qs[h + 1] + k0.y + k1.y + k2.y + k3.y);
    s += wvs[h + 2] * ftanh(qs[h + 2] + k0.z + k1.z + k2.z + k3.z);
    s += wvs[h + 3] * ftanh(qs[h + 3] + k0.w + k1.w + k2.w + k3.w);
  }
  const float mx = blockMax(s, red);
  const float e = __expf(s - mx);
  const float tot = blockSum(e, red);
  aw[tid] = e / tot;
  __syncthreads();

  // PV: acc = attn-row @ X3[b]; + residual (xrow, still original X3[b,lp,:]).
  float acc[5] = {0, 0, 0, 0, 0};
  const float* Xb = X3 + (size_t)b * SS * VEC;
  for (int j = 0; j < 256; ++j) {
    const float a = aw[j];
    const float* xr = Xb + (size_t)j * VEC;
#pragma unroll
    for (int k = 0; k < 5; ++k) acc[k] = fmaf(a, xr[tid + k * 256], acc[k]);
  }
  float sum = 0.0f;
#pragma unroll
  for (int k = 0; k < 5; ++k) {
    acc[k] += xrow[tid + k * 256];
    sum += acc[k];
  }
  sum = blockSum(sum, red);
  const float m = sum * (1.0f / VEC);
  float sq = 0.0f;
#pragma unroll
  for (int k = 0; k < 5; ++k) {
    const float dl = acc[k] - m;
    sq += dl * dl;
  }
  sq = blockSum(sq, red);
  const float rstd = rsqrtf(sq * (1.0f / VEC) + 1e-5f);
#pragma unroll
  for (int k = 0; k < 5; ++k) xrow[tid + k * 256] = (acc[k] - m) * rstd;
  __syncthreads();

  // Head: 1280 -> 32 (relu) -> 12 (relu) -> 2.
  {
    const int n = tid & 31, sl = tid >> 5;  // 8 K-slices of 160 per output
    float p = 0.0f;
    for (int k = sl * 160; k < sl * 160 + 160; ++k)
      p = fmaf(xrow[k], hW1[(size_t)k * 32 + n], p);
    partial[tid] = p;
  }
  __syncthreads();
  if (tid < 32) {
    float v = 0.0f;
#pragma unroll
    for (int s2 = 0; s2 < 8; ++s2) v += partial[s2 * 32 + tid];
    h1s[tid] = fmaxf(v + hb1[tid], 0.0f);
  }
  __syncthreads();
  if (tid < 12) {
    float v = 0.0f;
#pragma unroll
    for (int k = 0; k < 32; ++k) v = fmaf(h1s[k], hW2[k * 12 + tid], v);
    h2s[tid] = fmaxf(v + hb2[tid], 0.0f);
  }
  __syncthreads();
  if (tid < 2) {
    float v = 0.0f;
#pragma unroll
    for (int k = 0; k < 12; ++k) v = fmaf(h2s[k], hW3[k * 2 + tid], v);
    out[b * 2 + tid] = v + hb3[tid];
  }
}

// ---------------------------------------------------------------------------
extern "C" void kernel_launch(void* const* d_in, const int* in_sizes, int n_in,
                              void* d_out, int out_size, void* d_ws, size_t ws_size,
                              hipStream_t stream) {
  const float* X = (const float*)d_in[0];
  const int* lys = (const int*)d_in[1];
  const float* Wq[4] = {(const float*)d_in[2], (const float*)d_in[5],
                        (const float*)d_in[8], (const float*)d_in[11]};
  const float* Wk[4] = {(const float*)d_in[3], (const float*)d_in[6],
                        (const float*)d_in[9], (const float*)d_in[12]};
  const float* wv[4] = {(const float*)d_in[4], (const float*)d_in[7],
                        (const float*)d_in[10], (const float*)d_in[13]};
  const float* rW1[3] = {(const float*)d_in[14], (const float*)d_in[18],
                         (const float*)d_in[22]};
  const float* rb1[3] = {(const float*)d_in[15], (const float*)d_in[19],
                         (const float*)d_in[23]};
  const float* rW2[3] = {(const float*)d_in[16], (const float*)d_in[20],
                         (const float*)d_in[24]};
  const float* rb2[3] = {(const float*)d_in[17], (const float*)d_in[21],
                         (const float*)d_in[25]};
  const float* hW1 = (const float*)d_in[26];
  const float* hb1 = (const float*)d_in[27];
  const float* hW2 = (const float*)d_in[28];
  const float* hb2 = (const float*)d_in[29];
  const float* hW3 = (const float*)d_in[30];
  const float* hb3 = (const float*)d_in[31];
  float* out = (float*)d_out;

  // Workspace (floats), ~23 MB total.
  float* ws = (float*)d_ws;
  float* QKp  = ws;                    // 4 x 1024*256 partials
  float* attn = QKp + 4 * 262144;      // 1024*256
  float* big0 = attn + 262144;         // 1024*1280
  float* big1 = big0 + 1310720;        // 1024*1280
  float* Yb   = big1 + 1310720;        // 1024*1280
  float* Hp   = Yb + 1310720;          // 4 x 1024*128 partials

  const long QK_PS = 262144;   // QK partial stride
  const long H_PS  = 131072;   // FC1 / K4 partial stride
  const int NSPLIT_NONE = 1 << 30;

  // Layer l: in=P, attn-out(+res)=Q, post-LN=Yb, out=Q (ping-pong P/Q).
  const float* P[3] = {X, big0, big1};
  float* Q[3] = {big0, big1, big0};

  for (int l = 0; l < 3; ++l) {
    const float* Xin = P[l];
    // QKp[z] = Xin @ [Wq|Wk] over K-slice z (4 slices of 320).
    gemm_k<1, false, false, false><<<dim3(4, 16, 4), 256, 0, stream>>>(
        Xin, 0, 0, Wq[l], Wk[l], HID, 0, HID, QKp, QK_PS, nullptr, nullptr,
        nullptr, 256, VEC, 320);
    // attn = softmax(wv . tanh(q_i + k_j))  (sums QK partials inline)
    scores8_k<<<dim3(32, BB), 256, 0, stream>>>(QKp, QK_PS, wv[l], attn);
    // Q = attn @ Xin + Xin   (batched over b, residual fused)
    gemm_k<0, false, false, true><<<dim3(20, 4, 4), 256, 0, stream>>>(
        attn, (long)SS * SS, 0, Xin, Xin, NSPLIT_NONE, (long)SS * VEC, VEC,
        Q[l], (long)SS * VEC, nullptr, nullptr, Xin, VEC, SS, 0);
    // Yb = LN(Q)
    ln1_k<<<dim3(MROWS), 256, 0, stream>>>(Q[l], Yb);
    // Hp[z] = Yb @ rW1 over K-slice z (4 slices of 320).
    gemm_k<1, false, false, false><<<dim3(2, 16, 4), 256, 0, stream>>>(
        Yb, 0, 0, rW1[l], rW1[l], NSPLIT_NONE, 0, HID, Hp, H_PS, nullptr,
        nullptr, nullptr, HID, VEC, 320);
    // Q = relu(sum(Hp) + b1) @ rW2 + b2 + Yb
    gemm_k<0, true, true, true><<<dim3(20, 16, 1), 256, 0, stream>>>(
        Hp, 0, H_PS, rW2[l], rW2[l], NSPLIT_NONE, 0, VEC, Q[l], 0, rb1[l],
        rb2[l], Yb, VEC, HID, 0);
  }

  const float* X3 = Q[2];  // big0
  // Layer 4: K-proj only (partials into QKp region), then fused tail.
  gemm_k<1, false, false, false><<<dim3(2, 16, 4), 256, 0, stream>>>(
      X3, 0, 0, Wk[3], Wk[3], NSPLIT_NONE, 0, HID, QKp, H_PS, nullptr,
      nullptr, nullptr, HID, VEC, 320);
  tail4_k<<<dim3(BB), 256, 0, stream>>>(QKp, H_PS, X3, Wq[3], wv[3], lys,
                                        hW1, hb1, hW2, hb2, hW3, hb3, out);
}